// Round 9
// baseline (14026.205 us; speedup 1.0000x reference)
//
#include <hip/hip_runtime.h>
#include <hip/hip_bf16.h>
#include <math.h>

#define Bb 64
#define Tt 512
#define Dd 1024
#define Uu 1024
#define NWG 128      // persistent workgroups
#define UPW 8        // u's per WG
#define NCOL 32      // packed cols per WG = 4 gates * 8 u
#define KTOT 2048    // D + U packed K
#define KW 512       // K-half per wave pair
#define ZP 67        // z row stride (odd -> mixed banks)
#define HSLOT (Bb * Uu)  // bf16 elems per h ring slot (128 KB)

#define WLDS_BYTES 65536                      // 2 x 32KB Wh slices (conflict-free layout)
#define ZX_OFF WLDS_BYTES                     // zx[2][64][ZP] f32
#define ZH_OFF (WLDS_BYTES + 2 * Bb * ZP * 4) // zh[64][ZP] f32
#define DYN_LDS (WLDS_BYTES + 3 * Bb * ZP * 4)

typedef __attribute__((ext_vector_type(8))) short bf16x8;
typedef __attribute__((ext_vector_type(4))) float f32x4;
typedef __attribute__((ext_vector_type(2))) float f32x2;

// ---- one-time prep: pack W into per-WG transposed slices -------------------
// in: fp32 [K][4096]. out: pWT[(j*NCOL + pc)*KTOT + koff + k], pc = g*8+uu.
__global__ void pack_w(const float* __restrict__ in, __hip_bfloat16* __restrict__ pWT, int koff) {
  __shared__ float tile[32][33];
  int n0 = blockIdx.x * 32, k0 = blockIdx.y * 32;
  int tx = threadIdx.x, ty = threadIdx.y;
#pragma unroll
  for (int p = 0; p < 4; ++p) {
    int r = ty + p * 8;
    tile[r][tx] = in[(size_t)(k0 + r) * (4 * Uu) + n0 + tx];
  }
  __syncthreads();
#pragma unroll
  for (int p = 0; p < 4; ++p) {
    int r = ty + p * 8;
    int col = n0 + r;
    int j = (col & (Uu - 1)) >> 3;
    int g = col >> 10;
    int uu = col & 7;
    pWT[((size_t)(j * NCOL + g * UPW + uu)) * KTOT + koff + k0 + tx] = __float2bfloat16(tile[tx][r]);
  }
}

// ---- helpers ----------------------------------------------------------------

__device__ __forceinline__ unsigned pollSys(const unsigned* p) {
  return __hip_atomic_load(p, __ATOMIC_RELAXED, __HIP_MEMORY_SCOPE_SYSTEM);
}

#define WAITV(n)                                             \
  do {                                                       \
    asm volatile("s_waitcnt vmcnt(" #n ")" ::: "memory");    \
    __builtin_amdgcn_sched_barrier(0);                       \
  } while (0)

// h A-loads: sc0 (bypass L1, fill own-XCD L2; ring address is fresh -> never stale)
#define H_I(S, B)                                                              \
  {                                                                            \
    _Pragma("unroll") for (int kkr = 0; kkr < 2; ++kkr) {                      \
      _Pragma("unroll") for (int mt = 0; mt < 4; ++mt) {                       \
        asm volatile("global_load_dwordx4 %0, %1, off offset:%2 sc0"           \
                     : "=v"(S[kkr * 4 + mt])                                   \
                     : "v"(haddr[mt]), "i"((((B) * 2 + kkr) * 64))             \
                     : "memory");                                              \
      }                                                                        \
    }                                                                          \
  }

// Wh B-frag from LDS: lane-sequential 16B units -> conflict-free
#define WFRAG(kk, nt)                                                          \
  (*reinterpret_cast<const bf16x8*>(                                           \
      &wlds[(size_t)kh * 16384 + (((kk) * 2 + (nt)) * 64 + l15 * 4 + lk) * 8]))

#define H_C(S, B)                                                              \
  {                                                                            \
    _Pragma("unroll") for (int kkr = 0; kkr < 2; ++kkr) {                      \
      const int kk = (B) * 2 + kkr;                                            \
      bf16x8 w0 = WFRAG(kk, 0);                                                \
      bf16x8 w1 = WFRAG(kk, 1);                                                \
      _Pragma("unroll") for (int mt = 0; mt < 4; ++mt) {                       \
        bf16x8 af = __builtin_bit_cast(bf16x8, S[kkr * 4 + mt]);               \
        acc[mt][0] = __builtin_amdgcn_mfma_f32_16x16x32_bf16(af, w0, acc[mt][0], 0, 0, 0); \
        acc[mt][1] = __builtin_amdgcn_mfma_f32_16x16x32_bf16(af, w1, acc[mt][1], 0, 0, 0); \
      }                                                                        \
    }                                                                          \
  }

// x-GEMM: A from fp32 x (plain cached, converted in-register), B from L2 pWT
__device__ __forceinline__ void x_gemm(const float* __restrict__ xf,
                                       const __hip_bfloat16* __restrict__ wpx,
                                       int xt, int kofs, int l15, int lk,
                                       f32x4 (&acc)[4][2]) {
#pragma unroll
  for (int mt = 0; mt < 4; ++mt)
#pragma unroll
    for (int nt = 0; nt < 2; ++nt) acc[mt][nt] = (f32x4){0.f, 0.f, 0.f, 0.f};
#pragma unroll 2
  for (int kk = 0; kk < 16; ++kk) {
    bf16x8 w0 = *reinterpret_cast<const bf16x8*>(wpx + (size_t)(0 * 16 + l15) * KTOT + kofs + kk * 32 + lk * 8);
    bf16x8 w1 = *reinterpret_cast<const bf16x8*>(wpx + (size_t)(1 * 16 + l15) * KTOT + kofs + kk * 32 + lk * 8);
#pragma unroll
    for (int mt = 0; mt < 4; ++mt) {
      const float* xs = xf + ((size_t)(mt * 16 + l15) * Tt + xt) * Dd + kofs + kk * 32 + lk * 8;
      float4 fa = *reinterpret_cast<const float4*>(xs);
      float4 fb = *reinterpret_cast<const float4*>(xs + 4);
      union { bf16x8 v; __hip_bfloat16 e[8]; } u;
      u.e[0] = __float2bfloat16(fa.x); u.e[1] = __float2bfloat16(fa.y);
      u.e[2] = __float2bfloat16(fa.z); u.e[3] = __float2bfloat16(fa.w);
      u.e[4] = __float2bfloat16(fb.x); u.e[5] = __float2bfloat16(fb.y);
      u.e[6] = __float2bfloat16(fb.z); u.e[7] = __float2bfloat16(fb.w);
      acc[mt][0] = __builtin_amdgcn_mfma_f32_16x16x32_bf16(u.v, w0, acc[mt][0], 0, 0, 0);
      acc[mt][1] = __builtin_amdgcn_mfma_f32_16x16x32_bf16(u.v, w1, acc[mt][1], 0, 0, 0);
    }
  }
}

__device__ __forceinline__ void zwrite(float* zb, const f32x4 (&acc)[4][2], int lk, int l15) {
#pragma unroll
  for (int mt = 0; mt < 4; ++mt)
#pragma unroll
    for (int nt = 0; nt < 2; ++nt)
#pragma unroll
      for (int q = 0; q < 4; ++q)
        zb[(mt * 16 + lk * 4 + q) * ZP + nt * 16 + l15] = acc[mt][nt][q];
}
__device__ __forceinline__ void zrmw(float* zb, const f32x4 (&acc)[4][2], int lk, int l15) {
#pragma unroll
  for (int mt = 0; mt < 4; ++mt)
#pragma unroll
    for (int nt = 0; nt < 2; ++nt)
#pragma unroll
      for (int q = 0; q < 4; ++q)
        zb[(mt * 16 + lk * 4 + q) * ZP + nt * 16 + l15] += acc[mt][nt][q];
}

// ---- persistent LSTM --------------------------------------------------------
// 128 WGs x 256 thr. WG j owns u in [j*8, j*8+8) -> 32 packed cols (4 gates).
// wv0/wv1: zx(t+1) K-halves (x fp32->bf16 in-reg; Wx from L2). wv2/wv3: zh(t)
// K-halves (h from ring via sc0 cached loads; Wh from LDS, conflict-free).
// h(t) at a FRESH ring address each step -> cached reads never stale; one
// agent-acquire at launch start invalidates L2 poison from prior replays.
__launch_bounds__(256, 1)
__global__ void lstm_persist(const float* __restrict__ xf,
                             const __hip_bfloat16* __restrict__ pWT,
                             const float* __restrict__ bias,
                             const float* __restrict__ h0,
                             const float* __restrict__ c0,
                             __hip_bfloat16* __restrict__ hring,  // [Tt+1][B][U]
                             float* __restrict__ out,
                             unsigned* __restrict__ flags,        // [NWG][16]
                             unsigned* __restrict__ rel) {        // [16][16]
  extern __shared__ __align__(16) char smem[];
  __hip_bfloat16* wlds = (__hip_bfloat16*)smem;
  float* zxb = (float*)(smem + ZX_OFF);  // [2][64][ZP]
  float* zhb = (float*)(smem + ZH_OFF);  // [64][ZP]
  __shared__ unsigned gate;

  const int tid = threadIdx.x;
  const int wv = tid >> 6;
  const int lane = tid & 63;
  const int l15 = lane & 15;
  const int lk = lane >> 4;
  const int j = blockIdx.x;

  if (tid == 0) gate = 0;

  // --- Wh slices into LDS, lane-sequential 16B units (one-time)
  if (wv >= 2) {
    const int kh = wv - 2;
    const __hip_bfloat16* wp = pWT + (size_t)j * NCOL * KTOT + Dd + kh * KW;
#pragma unroll 2
    for (int kk = 0; kk < 16; ++kk)
#pragma unroll
      for (int nt = 0; nt < 2; ++nt) {
        bf16x8 v = *reinterpret_cast<const bf16x8*>(wp + (size_t)(nt * 16 + l15) * KTOT + kk * 32 + lk * 8);
        *reinterpret_cast<bf16x8*>(&wlds[(size_t)kh * 16384 + ((kk * 2 + nt) * 64 + l15 * 4 + lk) * 8]) = v;
      }
  }

  // --- epilogue ownership: one batch row, two adjacent u's
  const int eb = tid >> 2;
  const int eu = (tid & 3) * 2;
  const int u0 = j * UPW + eu;
  float bi0[4], bi1[4];
#pragma unroll
  for (int g = 0; g < 4; ++g) {
    bi0[g] = bias[g * Uu + u0];
    bi1[g] = bias[g * Uu + u0 + 1];
  }
  float cr0 = c0[(size_t)eb * Uu + u0];
  float cr1 = c0[(size_t)eb * Uu + u0 + 1];

  // --- init ring slot 0 = h0 (system-scope write-through)
  {
    union { __hip_bfloat162 v; unsigned u; } pk;
    pk.v.x = __float2bfloat16(h0[(size_t)eb * Uu + u0]);
    pk.v.y = __float2bfloat16(h0[(size_t)eb * Uu + u0 + 1]);
    __hip_atomic_store((unsigned*)hring + (((size_t)eb * Uu + u0) >> 1), pk.u,
                       __ATOMIC_RELAXED, __HIP_MEMORY_SCOPE_SYSTEM);
  }

  // --- one-time L2 invalidate (drops poison/stale lines from prior replays)
  {
    unsigned d = __hip_atomic_load(&flags[0], __ATOMIC_ACQUIRE, __HIP_MEMORY_SCOPE_AGENT);
    asm volatile("" ::"v"(d));
  }
  __syncthreads();  // wlds + gate ready

  const __hip_bfloat16* wpx = pWT + (size_t)j * NCOL * KTOT;

  // --- prologue: zx(0) into zx buffer 0
  {
    f32x4 acc[4][2];
    if (wv < 2) {
      x_gemm(xf, wpx, 0, wv * KW, l15, lk, acc);
      if (wv == 0) zwrite(zxb, acc, lk, l15);
      __syncthreads();
      if (wv == 1) zrmw(zxb, acc, lk, l15);
    } else {
      __syncthreads();
    }
  }

  for (int t = 0; t < Tt; ++t) {
    // S1: joins epilogue(t-1) + RMWs; drains vmcnt -> h(t) stores ack'd at MALL
    __syncthreads();

    const unsigned want = (unsigned)(t + 1);
    if (tid == 0)
      __hip_atomic_store(&flags[j * 16], want, __ATOMIC_RELAXED, __HIP_MEMORY_SCOPE_SYSTEM);

    f32x4 acc[4][2];

    if (wv < 2) {
      // ---- zx(t+1), off critical path
      const int xt = (t + 1 < Tt) ? t + 1 : t;
      x_gemm(xf, wpx, xt, wv * KW, l15, lk, acc);
      if (wv == 0) zwrite(zxb + (size_t)((t + 1) & 1) * Bb * ZP, acc, lk, l15);
    } else {
      const int kh = wv - 2;
      // ---- sync: flags -> aggregator(WG0.wv2) -> 16 rel replicas -> LDS gate
      if (wv == 2) {
        if (j == 0) {
          while (pollSys(&flags[lane * 16]) < want) __builtin_amdgcn_s_sleep(1);
          while (pollSys(&flags[(64 + lane) * 16]) < want) __builtin_amdgcn_s_sleep(1);
          if (lane < 16)
            __hip_atomic_store(&rel[lane * 16], want, __ATOMIC_RELAXED, __HIP_MEMORY_SCOPE_SYSTEM);
        } else {
          if (lane == 0)
            while (pollSys(&rel[(j & 15) * 16]) < want) __builtin_amdgcn_s_sleep(1);
        }
        if (lane == 0)
          __hip_atomic_store(&gate, want, __ATOMIC_RELAXED, __HIP_MEMORY_SCOPE_WORKGROUP);
      } else {
        while (__hip_atomic_load(&gate, __ATOMIC_RELAXED, __HIP_MEMORY_SCOPE_WORKGROUP) < want)
          __builtin_amdgcn_s_sleep(1);
      }
      __builtin_amdgcn_sched_barrier(0);

      // ---- zh(t): h from ring[t] via sc0 cached loads, 2-deep 2-kk batches
      const __hip_bfloat16* hcur = hring + (size_t)t * HSLOT;
      unsigned long long haddr[4];
#pragma unroll
      for (int mt = 0; mt < 4; ++mt)
        haddr[mt] = (unsigned long long)(hcur + (size_t)(mt * 16 + l15) * Uu + kh * KW) +
                    (unsigned long long)lk * 16;

      f32x4 s0[8], s1[8];
#pragma unroll
      for (int mt = 0; mt < 4; ++mt)
#pragma unroll
        for (int nt = 0; nt < 2; ++nt) acc[mt][nt] = (f32x4){0.f, 0.f, 0.f, 0.f};

      H_I(s0, 0); H_I(s1, 1);
      WAITV(8);  H_C(s0, 0); H_I(s0, 2);
      WAITV(8);  H_C(s1, 1); H_I(s1, 3);
      WAITV(8);  H_C(s0, 2); H_I(s0, 4);
      WAITV(8);  H_C(s1, 3); H_I(s1, 5);
      WAITV(8);  H_C(s0, 4); H_I(s0, 6);
      WAITV(8);  H_C(s1, 5); H_I(s1, 7);
      WAITV(8);  H_C(s0, 6);
      WAITV(0);  H_C(s1, 7);

      if (wv == 2) zwrite(zhb, acc, lk, l15);
    }

    __syncthreads();  // S2: writers done
    if (wv == 1) zrmw(zxb + (size_t)((t + 1) & 1) * Bb * ZP, acc, lk, l15);
    if (wv == 3) zrmw(zhb, acc, lk, l15);
    __syncthreads();  // S3: partials final

    // ---- epilogue(t): z = zx(t) + zh + bias; gates; emit
    const float* zxA = zxb + (size_t)(t & 1) * Bb * ZP;
    unsigned* hnxt32 = (unsigned*)(hring + (size_t)(t + 1) * HSLOT);
    float zz[4][2];
#pragma unroll
    for (int g = 0; g < 4; ++g) {
      const int idx = eb * ZP + g * UPW + eu;
      zz[g][0] = zxA[idx] + zhb[idx] + bi0[g];
      zz[g][1] = zxA[idx + 1] + zhb[idx + 1] + bi1[g];
    }
    float hv0, hv1;
    {
      float ig = 1.f / (1.f + __expf(-zz[0][0]));
      float fg = 1.f / (1.f + __expf(-zz[1][0]));
      float gg = tanhf(zz[2][0]);
      float og = 1.f / (1.f + __expf(-zz[3][0]));
      cr0 = fg * cr0 + ig * gg;
      hv0 = og * tanhf(cr0);
    }
    {
      float ig = 1.f / (1.f + __expf(-zz[0][1]));
      float fg = 1.f / (1.f + __expf(-zz[1][1]));
      float gg = tanhf(zz[2][1]);
      float og = 1.f / (1.f + __expf(-zz[3][1]));
      cr1 = fg * cr1 + ig * gg;
      hv1 = og * tanhf(cr1);
    }
    f32x2 o2 = {hv0, hv1};
    __builtin_nontemporal_store(o2, (f32x2*)(out + ((size_t)eb * Tt + t) * Uu + u0));
    {
      union { __hip_bfloat162 v; unsigned u; } pk;
      pk.v.x = __float2bfloat16(hv0);
      pk.v.y = __float2bfloat16(hv1);
      __hip_atomic_store(&hnxt32[((size_t)eb * Uu + u0) >> 1], pk.u,
                         __ATOMIC_RELAXED, __HIP_MEMORY_SCOPE_SYSTEM);
    }
  }
}

// ---- launch ----------------------------------------------------------------

extern "C" void kernel_launch(void* const* d_in, const int* in_sizes, int n_in,
                              void* d_out, int out_size, void* d_ws, size_t ws_size,
                              hipStream_t stream) {
  const float* x = (const float*)d_in[0];
  const float* h0 = (const float*)d_in[1];
  const float* c0 = (const float*)d_in[2];
  const float* Wx = (const float*)d_in[3];
  const float* Wh = (const float*)d_in[4];
  const float* bias = (const float*)d_in[5];
  float* out = (float*)d_out;

  char* ws = (char*)d_ws;
  size_t off = 0;
  __hip_bfloat16* pWT = (__hip_bfloat16*)(ws + off);   off += (size_t)NWG * NCOL * KTOT * 2;   // 16.8 MB
  __hip_bfloat16* hring = (__hip_bfloat16*)(ws + off); off += (size_t)(Tt + 1) * HSLOT * 2;    // 67.2 MB
  unsigned* flags = (unsigned*)(ws + off);             off += (size_t)NWG * 64;                // 8 KB
  unsigned* rel = (unsigned*)(ws + off);               off += (size_t)16 * 64;                 // 1 KB

  hipFuncSetAttribute((const void*)lstm_persist,
                      hipFuncAttributeMaxDynamicSharedMemorySize, DYN_LDS);

  pack_w<<<dim3(4 * Uu / 32, Dd / 32), dim3(32, 8), 0, stream>>>(Wx, pWT, 0);
  pack_w<<<dim3(4 * Uu / 32, Uu / 32), dim3(32, 8), 0, stream>>>(Wh, pWT, Dd);
  hipMemsetAsync(flags, 0, (size_t)NWG * 64 + 16 * 64, stream);

  lstm_persist<<<NWG, 256, DYN_LDS, stream>>>(x, pWT, bias, h0, c0, hring, out, flags, rel);
}

// Round 10
// 9591.680 us; speedup vs baseline: 1.4623x; 1.4623x over previous
//
#include <hip/hip_runtime.h>
#include <hip/hip_bf16.h>
#include <math.h>

#define Bb 64
#define Tt 512
#define Dd 1024
#define Uu 1024
#define NWG 128      // persistent workgroups
#define UPW 8        // u's per WG
#define NCOL 32      // packed cols per WG = 4 gates * 8 u
#define KTOT 2048    // D + U packed K
#define KW 512       // K-half per wave pair
#define ZP 67        // z row stride (odd -> mixed banks)

#define WLDS_BYTES 65536                      // 2 x 32KB Wh slices, conflict-free layout
#define ZX_OFF WLDS_BYTES                     // zx[2][64][ZP] f32
#define ZH_OFF (WLDS_BYTES + 2 * Bb * ZP * 4) // zh[64][ZP] f32
#define DYN_LDS (WLDS_BYTES + 3 * Bb * ZP * 4)

typedef __attribute__((ext_vector_type(8))) short bf16x8;
typedef __attribute__((ext_vector_type(4))) float f32x4;
typedef __attribute__((ext_vector_type(2))) float f32x2;

// ---- one-time prep --------------------------------------------------------

__global__ void cast_x_bf16(const float* __restrict__ in, __hip_bfloat16* __restrict__ out, int n4) {
  int i = blockIdx.x * blockDim.x + threadIdx.x;
  int stride = gridDim.x * blockDim.x;
  for (; i < n4; i += stride) {
    float4 v = reinterpret_cast<const float4*>(in)[i];
    __hip_bfloat16* o = out + 4 * (size_t)i;
    o[0] = __float2bfloat16(v.x);
    o[1] = __float2bfloat16(v.y);
    o[2] = __float2bfloat16(v.z);
    o[3] = __float2bfloat16(v.w);
  }
}

// in: fp32 [K][4096] (Wx or Wh). out: pWT[(j*NCOL + pc)*KTOT + koff + k], pc=g*8+uu.
__global__ void pack_w(const float* __restrict__ in, __hip_bfloat16* __restrict__ pWT, int koff) {
  __shared__ float tile[32][33];
  int n0 = blockIdx.x * 32, k0 = blockIdx.y * 32;
  int tx = threadIdx.x, ty = threadIdx.y;
#pragma unroll
  for (int p = 0; p < 4; ++p) {
    int r = ty + p * 8;
    tile[r][tx] = in[(size_t)(k0 + r) * (4 * Uu) + n0 + tx];
  }
  __syncthreads();
#pragma unroll
  for (int p = 0; p < 4; ++p) {
    int r = ty + p * 8;
    int col = n0 + r;
    int j = (col & (Uu - 1)) >> 3;
    int g = col >> 10;
    int uu = col & 7;
    pWT[((size_t)(j * NCOL + g * UPW + uu)) * KTOT + koff + k0 + tx] = __float2bfloat16(tile[tx][r]);
  }
}

// ---- helpers --------------------------------------------------------------

__device__ __forceinline__ unsigned pollSys(const unsigned* p) {
  return __hip_atomic_load(p, __ATOMIC_RELAXED, __HIP_MEMORY_SCOPE_SYSTEM);
}

#define WAITV(n)                                             \
  do {                                                       \
    asm volatile("s_waitcnt vmcnt(" #n ")" ::: "memory");    \
    __builtin_amdgcn_sched_barrier(0);                       \
  } while (0)

// h A-loads (fp32 source): sc0 = bypass L1, fill own-XCD L2. Source address is
// FRESH each step (out[:,t-1,:] / h0) -> cached reads can never be stale.
#define H_I(S, B)                                                              \
  {                                                                            \
    _Pragma("unroll") for (int mt = 0; mt < 4; ++mt) {                         \
      asm volatile("global_load_dwordx4 %0, %2, off offset:%3 sc0\n\t"         \
                   "global_load_dwordx4 %1, %2, off offset:%4 sc0"             \
                   : "=v"(S[mt * 2]), "=v"(S[mt * 2 + 1])                      \
                   : "v"(haddr[mt]), "i"((B) * 128), "i"((B) * 128 + 16)       \
                   : "memory");                                                \
    }                                                                          \
  }

// Wh B-frag from LDS: lane-sequential 16B units -> conflict-free
#define WFRAG(kk, nt)                                                          \
  (*reinterpret_cast<const bf16x8*>(                                           \
      &wlds[(size_t)kh * 16384 + (((kk) * 2 + (nt)) * 64 + l15 * 4 + lk) * 8]))

#define H_C(S, B)                                                              \
  {                                                                            \
    bf16x8 w0 = WFRAG(B, 0);                                                   \
    bf16x8 w1 = WFRAG(B, 1);                                                   \
    _Pragma("unroll") for (int mt = 0; mt < 4; ++mt) {                         \
      f32x4 fa = S[mt * 2], fb = S[mt * 2 + 1];                                \
      union { bf16x8 v; __hip_bfloat16 e[8]; } u;                              \
      u.e[0] = __float2bfloat16(fa[0]); u.e[1] = __float2bfloat16(fa[1]);      \
      u.e[2] = __float2bfloat16(fa[2]); u.e[3] = __float2bfloat16(fa[3]);      \
      u.e[4] = __float2bfloat16(fb[0]); u.e[5] = __float2bfloat16(fb[1]);      \
      u.e[6] = __float2bfloat16(fb[2]); u.e[7] = __float2bfloat16(fb[3]);      \
      acc[mt][0] = __builtin_amdgcn_mfma_f32_16x16x32_bf16(u.v, w0, acc[mt][0], 0, 0, 0); \
      acc[mt][1] = __builtin_amdgcn_mfma_f32_16x16x32_bf16(u.v, w1, acc[mt][1], 0, 0, 0); \
    }                                                                          \
  }

// x-GEMM: A from bf16 xb (plain cached), B from L2-resident pWT
__device__ __forceinline__ void x_gemm(const __hip_bfloat16* __restrict__ xb,
                                       const __hip_bfloat16* __restrict__ wpx,
                                       int xt, int kofs, int l15, int lk,
                                       f32x4 (&acc)[4][2]) {
#pragma unroll
  for (int mt = 0; mt < 4; ++mt)
#pragma unroll
    for (int nt = 0; nt < 2; ++nt) acc[mt][nt] = (f32x4){0.f, 0.f, 0.f, 0.f};
  const __hip_bfloat16* asrc = xb + (size_t)xt * Dd + kofs;
#pragma unroll 4
  for (int kk = 0; kk < 16; ++kk) {
    bf16x8 w0 = *reinterpret_cast<const bf16x8*>(wpx + (size_t)(0 * 16 + l15) * KTOT + kofs + kk * 32 + lk * 8);
    bf16x8 w1 = *reinterpret_cast<const bf16x8*>(wpx + (size_t)(1 * 16 + l15) * KTOT + kofs + kk * 32 + lk * 8);
#pragma unroll
    for (int mt = 0; mt < 4; ++mt) {
      bf16x8 af = *reinterpret_cast<const bf16x8*>(asrc + (size_t)(mt * 16 + l15) * Tt * Dd + kk * 32 + lk * 8);
      acc[mt][0] = __builtin_amdgcn_mfma_f32_16x16x32_bf16(af, w0, acc[mt][0], 0, 0, 0);
      acc[mt][1] = __builtin_amdgcn_mfma_f32_16x16x32_bf16(af, w1, acc[mt][1], 0, 0, 0);
    }
  }
}

__device__ __forceinline__ void zwrite(float* zb, const f32x4 (&acc)[4][2], int lk, int l15) {
#pragma unroll
  for (int mt = 0; mt < 4; ++mt)
#pragma unroll
    for (int nt = 0; nt < 2; ++nt)
#pragma unroll
      for (int q = 0; q < 4; ++q)
        zb[(mt * 16 + lk * 4 + q) * ZP + nt * 16 + l15] = acc[mt][nt][q];
}
__device__ __forceinline__ void zrmw(float* zb, const f32x4 (&acc)[4][2], int lk, int l15) {
#pragma unroll
  for (int mt = 0; mt < 4; ++mt)
#pragma unroll
    for (int nt = 0; nt < 2; ++nt)
#pragma unroll
      for (int q = 0; q < 4; ++q)
        zb[(mt * 16 + lk * 4 + q) * ZP + nt * 16 + l15] += acc[mt][nt][q];
}

// ---- persistent LSTM -------------------------------------------------------
// 128 WGs x 256 thr. WG j owns u in [j*8, j*8+8) -> 32 packed cols (4 gates).
// wv0/wv1: zx(t+1) K-halves (xb bf16 + Wx from L2; off critical path).
// wv2/wv3: zh(t) K-halves; h(t) read from out[:,t-1,:] (fp32, fresh address
// per step -> sc0 L2-cached reads are never stale; 16 WGs/XCD share one L2
// fill). Wh in LDS (conflict-free). out stores are system-scope so the next
// step's readers see them at MALL; one agent-acquire L2 inv at start covers
// graph replays. Sync: 128 flags -> WG0.wv2 -> 16 rel replicas -> LDS gate.
__launch_bounds__(256, 1)
__global__ void lstm_persist(const __hip_bfloat16* __restrict__ xb,
                             const __hip_bfloat16* __restrict__ pWT,
                             const float* __restrict__ bias,
                             const float* __restrict__ h0,
                             const float* __restrict__ c0,
                             float* __restrict__ out,          // [B][T][U] == h ring
                             unsigned* __restrict__ flags,     // [NWG][16]
                             unsigned* __restrict__ rel) {     // [16][16]
  extern __shared__ __align__(16) char smem[];
  __hip_bfloat16* wlds = (__hip_bfloat16*)smem;
  float* zxb = (float*)(smem + ZX_OFF);  // [2][64][ZP]
  float* zhb = (float*)(smem + ZH_OFF);  // [64][ZP]
  __shared__ unsigned gate;

  const int tid = threadIdx.x;
  const int wv = tid >> 6;
  const int lane = tid & 63;
  const int l15 = lane & 15;
  const int lk = lane >> 4;
  const int j = blockIdx.x;

  if (tid == 0) gate = 0;

  // --- Wh slices into LDS, lane-sequential 16B units (one-time)
  if (wv >= 2) {
    const int kh = wv - 2;
    const __hip_bfloat16* wp = pWT + (size_t)j * NCOL * KTOT + Dd + kh * KW;
#pragma unroll 2
    for (int kk = 0; kk < 16; ++kk)
#pragma unroll
      for (int nt = 0; nt < 2; ++nt) {
        bf16x8 v = *reinterpret_cast<const bf16x8*>(wp + (size_t)(nt * 16 + l15) * KTOT + kk * 32 + lk * 8);
        *reinterpret_cast<bf16x8*>(&wlds[(size_t)kh * 16384 + ((kk * 2 + nt) * 64 + l15 * 4 + lk) * 8]) = v;
      }
  }

  // --- epilogue ownership: one batch row, two adjacent u's
  const int eb = tid >> 2;
  const int eu = (tid & 3) * 2;
  const int u0 = j * UPW + eu;
  float bi0[4], bi1[4];
#pragma unroll
  for (int g = 0; g < 4; ++g) {
    bi0[g] = bias[g * Uu + u0];
    bi1[g] = bias[g * Uu + u0 + 1];
  }
  float cr0 = c0[(size_t)eb * Uu + u0];
  float cr1 = c0[(size_t)eb * Uu + u0 + 1];

  // --- one-time agent-acquire: L2 invalidate (drops stale lines from replays)
  {
    unsigned d = __hip_atomic_load(&flags[0], __ATOMIC_ACQUIRE, __HIP_MEMORY_SCOPE_AGENT);
    asm volatile("" ::"v"(d));
  }
  __syncthreads();  // wlds + gate ready

  const __hip_bfloat16* wpx = pWT + (size_t)j * NCOL * KTOT;

  // --- prologue: zx(0) into zx buffer 0
  {
    f32x4 acc[4][2];
    if (wv < 2) {
      x_gemm(xb, wpx, 0, wv * KW, l15, lk, acc);
      if (wv == 0) zwrite(zxb, acc, lk, l15);
    }
    __syncthreads();
    if (wv == 1) zrmw(zxb, acc, lk, l15);
  }

  for (int t = 0; t < Tt; ++t) {
    // S1: joins epilogue(t-1)+RMWs; drains vmcnt -> out(t-1) stores at MALL
    __syncthreads();

    const unsigned want = (unsigned)(t + 1);
    if (tid == 0)
      __hip_atomic_store(&flags[j * 16], want, __ATOMIC_RELAXED, __HIP_MEMORY_SCOPE_SYSTEM);

    f32x4 acc[4][2];

    if (wv < 2) {
      // ---- zx(t+1), off critical path
      const int xt = (t + 1 < Tt) ? t + 1 : t;
      x_gemm(xb, wpx, xt, wv * KW, l15, lk, acc);
      if (wv == 0) zwrite(zxb + (size_t)((t + 1) & 1) * Bb * ZP, acc, lk, l15);
    } else {
      const int kh = wv - 2;
      // ---- sync: flags -> aggregator(WG0.wv2) -> 16 rel replicas -> LDS gate
      if (wv == 2) {
        if (j == 0) {
          while (pollSys(&flags[lane * 16]) < want) __builtin_amdgcn_s_sleep(1);
          while (pollSys(&flags[(64 + lane) * 16]) < want) __builtin_amdgcn_s_sleep(1);
          if (lane < 16)
            __hip_atomic_store(&rel[lane * 16], want, __ATOMIC_RELAXED, __HIP_MEMORY_SCOPE_SYSTEM);
        } else {
          if (lane == 0)
            while (pollSys(&rel[(j & 15) * 16]) < want) __builtin_amdgcn_s_sleep(1);
        }
        if (lane == 0)
          __hip_atomic_store(&gate, want, __ATOMIC_RELAXED, __HIP_MEMORY_SCOPE_WORKGROUP);
      } else {
        while (__hip_atomic_load(&gate, __ATOMIC_RELAXED, __HIP_MEMORY_SCOPE_WORKGROUP) < want)
          __builtin_amdgcn_s_sleep(1);
      }
      __builtin_amdgcn_sched_barrier(0);

      // ---- zh(t): h from h0 (t=0) or out[:,t-1,:], sc0-cached fp32 loads
      const float* hsrc = (t == 0) ? h0 : (out + (size_t)(t - 1) * Uu);
      const size_t hstride = (t == 0) ? (size_t)Uu : (size_t)Tt * Uu;
      unsigned long long haddr[4];
#pragma unroll
      for (int mt = 0; mt < 4; ++mt)
        haddr[mt] = (unsigned long long)(hsrc + (size_t)(mt * 16 + l15) * hstride + kh * KW) +
                    (unsigned long long)lk * 32;

      f32x4 s0[8], s1[8];
#pragma unroll
      for (int mt = 0; mt < 4; ++mt)
#pragma unroll
        for (int nt = 0; nt < 2; ++nt) acc[mt][nt] = (f32x4){0.f, 0.f, 0.f, 0.f};

      H_I(s0, 0); H_I(s1, 1);
      WAITV(8);  H_C(s0, 0);  H_I(s0, 2);
      WAITV(8);  H_C(s1, 1);  H_I(s1, 3);
      WAITV(8);  H_C(s0, 2);  H_I(s0, 4);
      WAITV(8);  H_C(s1, 3);  H_I(s1, 5);
      WAITV(8);  H_C(s0, 4);  H_I(s0, 6);
      WAITV(8);  H_C(s1, 5);  H_I(s1, 7);
      WAITV(8);  H_C(s0, 6);  H_I(s0, 8);
      WAITV(8);  H_C(s1, 7);  H_I(s1, 9);
      WAITV(8);  H_C(s0, 8);  H_I(s0, 10);
      WAITV(8);  H_C(s1, 9);  H_I(s1, 11);
      WAITV(8);  H_C(s0, 10); H_I(s0, 12);
      WAITV(8);  H_C(s1, 11); H_I(s1, 13);
      WAITV(8);  H_C(s0, 12); H_I(s0, 14);
      WAITV(8);  H_C(s1, 13); H_I(s1, 15);
      WAITV(8);  H_C(s0, 14);
      WAITV(0);  H_C(s1, 15);

      if (wv == 2) zwrite(zhb, acc, lk, l15);
    }

    __syncthreads();  // S2: writers done
    if (wv == 1) zrmw(zxb + (size_t)((t + 1) & 1) * Bb * ZP, acc, lk, l15);
    if (wv == 3) zrmw(zhb, acc, lk, l15);
    __syncthreads();  // S3: partials final

    // ---- epilogue(t): z = zx(t) + zh + bias; gates; emit h(t+1) -> out
    const float* zxA = zxb + (size_t)(t & 1) * Bb * ZP;
    float zz[4][2];
#pragma unroll
    for (int g = 0; g < 4; ++g) {
      const int idx = eb * ZP + g * UPW + eu;
      zz[g][0] = zxA[idx] + zhb[idx] + bi0[g];
      zz[g][1] = zxA[idx + 1] + zhb[idx + 1] + bi1[g];
    }
    float hv0, hv1;
    {
      float ig = 1.f / (1.f + __expf(-zz[0][0]));
      float fg = 1.f / (1.f + __expf(-zz[1][0]));
      float gg = tanhf(zz[2][0]);
      float og = 1.f / (1.f + __expf(-zz[3][0]));
      cr0 = fg * cr0 + ig * gg;
      hv0 = og * tanhf(cr0);
    }
    {
      float ig = 1.f / (1.f + __expf(-zz[0][1]));
      float fg = 1.f / (1.f + __expf(-zz[1][1]));
      float gg = tanhf(zz[2][1]);
      float og = 1.f / (1.f + __expf(-zz[3][1]));
      cr1 = fg * cr1 + ig * gg;
      hv1 = og * tanhf(cr1);
    }
    {
      union { f32x2 v; unsigned long long q; } o;
      o.v = (f32x2){hv0, hv1};
      unsigned long long* op = (unsigned long long*)(out + ((size_t)eb * Tt + t) * Uu + u0);
      __hip_atomic_store(op, o.q, __ATOMIC_RELAXED, __HIP_MEMORY_SCOPE_SYSTEM);
    }
  }
}

// ---- launch ----------------------------------------------------------------

extern "C" void kernel_launch(void* const* d_in, const int* in_sizes, int n_in,
                              void* d_out, int out_size, void* d_ws, size_t ws_size,
                              hipStream_t stream) {
  const float* x = (const float*)d_in[0];
  const float* h0 = (const float*)d_in[1];
  const float* c0 = (const float*)d_in[2];
  const float* Wx = (const float*)d_in[3];
  const float* Wh = (const float*)d_in[4];
  const float* bias = (const float*)d_in[5];
  float* out = (float*)d_out;

  char* ws = (char*)d_ws;
  size_t off = 0;
  __hip_bfloat16* xb = (__hip_bfloat16*)(ws + off);  off += (size_t)Bb * Tt * Dd * 2;       // 64 MB
  __hip_bfloat16* pWT = (__hip_bfloat16*)(ws + off); off += (size_t)NWG * NCOL * KTOT * 2;  // 16.8 MB
  unsigned* flags = (unsigned*)(ws + off);           off += (size_t)NWG * 64;               // 8 KB
  unsigned* rel = (unsigned*)(ws + off);             off += (size_t)16 * 64;                // 1 KB

  hipFuncSetAttribute((const void*)lstm_persist,
                      hipFuncAttributeMaxDynamicSharedMemorySize, DYN_LDS);

  cast_x_bf16<<<4096, 256, 0, stream>>>(x, xb, Bb * Tt * Dd / 4);
  pack_w<<<dim3(4 * Uu / 32, Dd / 32), dim3(32, 8), 0, stream>>>(Wx, pWT, 0);
  pack_w<<<dim3(4 * Uu / 32, Uu / 32), dim3(32, 8), 0, stream>>>(Wh, pWT, Dd);
  hipMemsetAsync(flags, 0, (size_t)NWG * 64 + 16 * 64, stream);

  lstm_persist<<<NWG, 256, DYN_LDS, stream>>>(xb, pWT, bias, h0, c0, out, flags, rel);
}

// Round 11
// 7631.773 us; speedup vs baseline: 1.8379x; 1.2568x over previous
//
#include <hip/hip_runtime.h>
#include <hip/hip_bf16.h>
#include <math.h>

#define Bb 64
#define Tt 512
#define Dd 1024
#define Uu 1024
#define NHW 64        // h-recurrence WGs (the only synchronized set)
#define NXW 128       // xz-producer WGs (2 feeders per h-WG: K-halves of D)
#define NWG (NHW + NXW)
#define ZP 68         // zpart row stride (floats); (68r+c)%32 -> <=2-way banks
#define NSLOT 8       // xz ring depth
#define GUARD (1 << 22)

typedef __attribute__((ext_vector_type(8))) short bf16x8;
typedef __attribute__((ext_vector_type(4))) float f32x4;

#define DYN_LDS (4 * Bb * ZP * 4)  // zpart[4][64][68] f32 = 69632 B

// ---- one-time weight packing ----------------------------------------------
// Wh fp32 [1024][4096] -> pWh[(c*64 + pc)*1024 + k] bf16, c=(col&1023)>>4,
// pc = (col>>10)*16 + (col&15)  (ct tile == gate)
__global__ void pack_wh(const float* __restrict__ in, __hip_bfloat16* __restrict__ dst) {
  __shared__ float tile[32][33];
  int n0 = blockIdx.x * 32, k0 = blockIdx.y * 32;
  int tx = threadIdx.x, ty = threadIdx.y;
#pragma unroll
  for (int p = 0; p < 4; ++p) {
    int r = ty + p * 8;
    tile[r][tx] = in[(size_t)(k0 + r) * (4 * Uu) + n0 + tx];
  }
  __syncthreads();
#pragma unroll
  for (int p = 0; p < 4; ++p) {
    int r = ty + p * 8;
    int col = n0 + r;
    int c = (col & (Uu - 1)) >> 4;
    int pc = (col >> 10) * 16 + (col & 15);
    dst[((size_t)c * 64 + pc) * 1024 + k0 + tx] = __float2bfloat16(tile[tx][r]);
  }
}

// Wx fp32 [1024][4096] -> pWx[((c*2+half)*64 + pc)*512 + (k&511)], half = k>>9
__global__ void pack_wx(const float* __restrict__ in, __hip_bfloat16* __restrict__ dst) {
  __shared__ float tile[32][33];
  int n0 = blockIdx.x * 32, k0 = blockIdx.y * 32;
  int tx = threadIdx.x, ty = threadIdx.y;
#pragma unroll
  for (int p = 0; p < 4; ++p) {
    int r = ty + p * 8;
    tile[r][tx] = in[(size_t)(k0 + r) * (4 * Uu) + n0 + tx];
  }
  __syncthreads();
#pragma unroll
  for (int p = 0; p < 4; ++p) {
    int r = ty + p * 8;
    int col = n0 + r;
    int c = (col & (Uu - 1)) >> 4;
    int pc = (col >> 10) * 16 + (col & 15);
    int k = k0 + tx;
    dst[(((size_t)c * 2 + (k >> 9)) * 64 + pc) * 512 + (k & 511)] = __float2bfloat16(tile[tx][r]);
  }
}

// ---- helpers ---------------------------------------------------------------

__device__ __forceinline__ unsigned pollSys(const unsigned* p) {
  return __hip_atomic_load(p, __ATOMIC_RELAXED, __HIP_MEMORY_SCOPE_SYSTEM);
}
__device__ __forceinline__ void storeSys(unsigned* p, unsigned v) {
  __hip_atomic_store(p, v, __ATOMIC_RELAXED, __HIP_MEMORY_SCOPE_SYSTEM);
}

#define WAITV(n)                                             \
  do {                                                       \
    asm volatile("s_waitcnt vmcnt(" #n ")" ::: "memory");    \
    __builtin_amdgcn_sched_barrier(0);                       \
  } while (0)

// batch = 1 kk: 8 A-loads (fp32 pairs) + 4 B-loads (bf16) = 12 loads, 48 VGPR
#define ISSUE_H(S, kk)                                                         \
  {                                                                            \
    _Pragma("unroll") for (int mt = 0; mt < 4; ++mt) {                         \
      asm volatile("global_load_dwordx4 %0, %2, off offset:%3 sc0\n\t"         \
                   "global_load_dwordx4 %1, %2, off offset:%4 sc0"             \
                   : "=&v"(S[mt * 2]), "=&v"(S[mt * 2 + 1])                    \
                   : "v"(haddr[mt]), "i"((kk) * 128), "i"((kk) * 128 + 16)     \
                   : "memory");                                                \
    }                                                                          \
    _Pragma("unroll") for (int ct = 0; ct < 4; ++ct) {                         \
      asm volatile("global_load_dwordx4 %0, %1, off offset:%2"                 \
                   : "=&v"(S[8 + ct]) : "v"(baddr[ct]), "i"((kk) * 64)         \
                   : "memory");                                                \
    }                                                                          \
  }

#define ISSUE_X(S, kk)                                                         \
  {                                                                            \
    _Pragma("unroll") for (int mt = 0; mt < 4; ++mt) {                         \
      asm volatile("global_load_dwordx4 %0, %2, off offset:%3\n\t"             \
                   "global_load_dwordx4 %1, %2, off offset:%4"                 \
                   : "=&v"(S[mt * 2]), "=&v"(S[mt * 2 + 1])                    \
                   : "v"(xaddr[mt]), "i"((kk) * 128), "i"((kk) * 128 + 16)     \
                   : "memory");                                                \
    }                                                                          \
    _Pragma("unroll") for (int ct = 0; ct < 4; ++ct) {                         \
      asm volatile("global_load_dwordx4 %0, %1, off offset:%2"                 \
                   : "=&v"(S[8 + ct]) : "v"(baddr[ct]), "i"((kk) * 64)         \
                   : "memory");                                                \
    }                                                                          \
  }

#define CONSUME(S)                                                             \
  {                                                                            \
    _Pragma("unroll") for (int mt = 0; mt < 4; ++mt) {                         \
      f32x4 fa = S[mt * 2], fb = S[mt * 2 + 1];                                \
      union { bf16x8 v; __hip_bfloat16 e[8]; } u;                              \
      u.e[0] = __float2bfloat16(fa[0]); u.e[1] = __float2bfloat16(fa[1]);      \
      u.e[2] = __float2bfloat16(fa[2]); u.e[3] = __float2bfloat16(fa[3]);      \
      u.e[4] = __float2bfloat16(fb[0]); u.e[5] = __float2bfloat16(fb[1]);      \
      u.e[6] = __float2bfloat16(fb[2]); u.e[7] = __float2bfloat16(fb[3]);      \
      _Pragma("unroll") for (int ct = 0; ct < 4; ++ct)                         \
        acc[mt][ct] = __builtin_amdgcn_mfma_f32_16x16x32_bf16(                 \
            u.v, __builtin_bit_cast(bf16x8, S[8 + ct]), acc[mt][ct], 0, 0, 0); \
    }                                                                          \
  }

#define LOADXZ(D, ap, off)                                                     \
  asm volatile("global_load_dwordx4 %0, %1, off offset:%2 sc0 sc1"             \
               : "=&v"(D) : "v"(ap), "i"(off) : "memory");
#define STORE16_WT(ap, off, D)                                                 \
  asm volatile("global_store_dwordx4 %0, %1, off offset:%2 sc0 sc1"            \
               :: "v"(ap), "v"(D), "i"(off) : "memory");

__device__ __forceinline__ float sigm(float v) { return 1.f / (1.f + __expf(-v)); }

// ---- persistent LSTM -------------------------------------------------------
// 192 WGs x 256 thr, all co-resident (<=256 CUs, 1 WG/CU).
// WGs 0..63   (h-WGs): the recurrence. WG c owns u in [c*16,c*16+16) (128 cols,
//   ct tile == gate). 4 waves K-split 256. h(t) read from out[:,t-1,:] via sc0
//   (fresh address per step -> L2-cached reads never stale). Barrier among the
//   64 h-WGs only: single-hop all-to-all flag matrix.
// WGs 64..191 (x-WGs): idx=(c,half). Produce xz partial (K-half of D) for h-WG
//   c into an 8-slot fp32 ring; post per-(c,half) slot flags; throttle on
//   consumed[c]. Entirely off the sequential critical path.
__launch_bounds__(256, 1)
__global__ void lstm_persist(const float* __restrict__ x,
                             const __hip_bfloat16* __restrict__ pWh,
                             const __hip_bfloat16* __restrict__ pWx,
                             const float* __restrict__ bias,
                             const float* __restrict__ h0,
                             const float* __restrict__ c0,
                             float* out,                        // [B][T][U] == h ring
                             float* __restrict__ xzring,        // [8][128][64][128] f32
                             unsigned* __restrict__ flagmat,    // [64 cons][64 prod]
                             unsigned* __restrict__ xzflag,     // [128][16] 64B lines
                             unsigned* __restrict__ consumed) { // [64][16] 64B lines
  extern __shared__ __align__(16) float zpart[];  // [4][64][ZP]
  const int tid = threadIdx.x;
  const int wv = tid >> 6;
  const int lane = tid & 63;
  const int l15 = lane & 15;
  const int lk = lane >> 4;
  const int j = blockIdx.x;

#define ZPART(w, r, cc) zpart[(((w) * Bb + (r)) * ZP) + (cc)]

  // one-time agent-acquire: invalidate L2 stale lines from prior graph replays
  {
    unsigned d = __hip_atomic_load(flagmat, __ATOMIC_ACQUIRE, __HIP_MEMORY_SCOPE_AGENT);
    asm volatile("" ::"v"(d));
  }

  f32x4 s0[12], s1[12];
  f32x4 acc[4][4];

  if (j < NHW) {
    // ================= h-WG =================
    const int c = j;
    unsigned long long baddr[4];
#pragma unroll
    for (int ct = 0; ct < 4; ++ct)
      baddr[ct] = (unsigned long long)(pWh + ((size_t)(c * 64 + ct * 16 + l15)) * 1024 + wv * 256) +
                  (unsigned long long)lk * 16;

    // epilogue state: row r, 4 u's
    const int r = tid >> 2;
    const int uu0 = (tid & 3) * 4;
    const int u0 = c * 16 + uu0;
    f32x4 bi[4];
#pragma unroll
    for (int g = 0; g < 4; ++g)
      bi[g] = *reinterpret_cast<const f32x4*>(bias + (size_t)g * Uu + u0);
    f32x4 cr = *reinterpret_cast<const f32x4*>(c0 + (size_t)r * Uu + u0);

    for (int t = 0; t < Tt; ++t) {
      // ---- gate: h(t) ready (all-to-all row) + xz(t) ready (2 feeder flags)
      if (wv == 0) {
        if (t > 0) {
          const unsigned* fp = flagmat + c * 64 + lane;
          int gd = 0;
          while (pollSys(fp) < (unsigned)t && ++gd < GUARD) __builtin_amdgcn_s_sleep(2);
        }
        if (lane == 0) {
          int gd = 0;
          while (pollSys(&xzflag[(c * 2 + 0) * 16]) < (unsigned)(t + 1) && ++gd < GUARD)
            __builtin_amdgcn_s_sleep(2);
          gd = 0;
          while (pollSys(&xzflag[(c * 2 + 1) * 16]) < (unsigned)(t + 1) && ++gd < GUARD)
            __builtin_amdgcn_s_sleep(2);
        }
      }
      __syncthreads();  // G1

      // ---- h-GEMM: A = h(t) fp32 via sc0 (L2-shared), B = pWh (plain/L2)
      const float* hsrc = (t == 0) ? h0 : (out + (size_t)(t - 1) * Uu);
      const size_t hstr = (t == 0) ? (size_t)Uu : (size_t)Tt * Uu;
      unsigned long long haddr[4];
#pragma unroll
      for (int mt = 0; mt < 4; ++mt)
        haddr[mt] = (unsigned long long)(hsrc + (size_t)(mt * 16 + l15) * hstr + wv * 256) +
                    (unsigned long long)lk * 32;
#pragma unroll
      for (int mt = 0; mt < 4; ++mt)
#pragma unroll
        for (int ct = 0; ct < 4; ++ct) acc[mt][ct] = (f32x4){0.f, 0.f, 0.f, 0.f};

      ISSUE_H(s0, 0); ISSUE_H(s1, 1);
      WAITV(12); CONSUME(s0); ISSUE_H(s0, 2);
      WAITV(12); CONSUME(s1); ISSUE_H(s1, 3);
      WAITV(12); CONSUME(s0); ISSUE_H(s0, 4);
      WAITV(12); CONSUME(s1); ISSUE_H(s1, 5);
      WAITV(12); CONSUME(s0); ISSUE_H(s0, 6);
      WAITV(12); CONSUME(s1); ISSUE_H(s1, 7);
      WAITV(12); CONSUME(s0);
      WAITV(0);  CONSUME(s1);

#pragma unroll
      for (int mt = 0; mt < 4; ++mt)
#pragma unroll
        for (int ct = 0; ct < 4; ++ct)
#pragma unroll
          for (int q = 0; q < 4; ++q)
            ZPART(wv, mt * 16 + lk * 4 + q, ct * 16 + l15) = acc[mt][ct][q];
      __syncthreads();  // G2

      // ---- epilogue: z = sum zpart[0..3] + xz halves + bias; gates; emit
      {
        const size_t xzs = ((size_t)(t & (NSLOT - 1)) * 128 + c * 2) * 8192 +
                           (size_t)r * 128 + uu0;
        unsigned long long xa0 = (unsigned long long)(xzring + xzs);
        unsigned long long xa1 = (unsigned long long)(xzring + xzs + 8192);
        f32x4 xz0[4], xz1[4];
        LOADXZ(xz0[0], xa0, 0);   LOADXZ(xz0[1], xa0, 64);
        LOADXZ(xz0[2], xa0, 128); LOADXZ(xz0[3], xa0, 192);
        LOADXZ(xz1[0], xa1, 0);   LOADXZ(xz1[1], xa1, 64);
        LOADXZ(xz1[2], xa1, 128); LOADXZ(xz1[3], xa1, 192);
        WAITV(0);
        f32x4 zz[4];
#pragma unroll
        for (int g = 0; g < 4; ++g) {
          const int cc = g * 16 + uu0;
          f32x4 s = *reinterpret_cast<const f32x4*>(&ZPART(0, r, cc));
#pragma unroll
          for (int w = 1; w < 4; ++w) {
            f32x4 v = *reinterpret_cast<const f32x4*>(&ZPART(w, r, cc));
            s[0] += v[0]; s[1] += v[1]; s[2] += v[2]; s[3] += v[3];
          }
          zz[g][0] = s[0] + xz0[g][0] + xz1[g][0] + bi[g][0];
          zz[g][1] = s[1] + xz0[g][1] + xz1[g][1] + bi[g][1];
          zz[g][2] = s[2] + xz0[g][2] + xz1[g][2] + bi[g][2];
          zz[g][3] = s[3] + xz0[g][3] + xz1[g][3] + bi[g][3];
        }
        f32x4 hv;
#pragma unroll
        for (int i = 0; i < 4; ++i) {
          float ig = sigm(zz[0][i]);
          float fg = sigm(zz[1][i]);
          float gg = tanhf(zz[2][i]);
          float og = sigm(zz[3][i]);
          cr[i] = fg * cr[i] + ig * gg;
          hv[i] = og * tanhf(cr[i]);
        }
        unsigned long long oa =
            (unsigned long long)(out + ((size_t)r * Tt + t) * Uu + u0);
        STORE16_WT(oa, 0, hv);
      }
      __syncthreads();  // G3: drains all waves' stores (vmcnt) -> MALL-visible

      if (wv == 0) {
        storeSys(&flagmat[lane * 64 + c], (unsigned)(t + 1));   // h(t+1) ready
        if (lane == 0) storeSys(&consumed[c * 16], (unsigned)(t + 1));
      }
    }
  } else {
    // ================= x-WG =================
    const int idx = j - NHW;
    const int c = idx >> 1, half = idx & 1;
    unsigned long long baddr[4];
#pragma unroll
    for (int ct = 0; ct < 4; ++ct)
      baddr[ct] = (unsigned long long)(pWx + ((size_t)(idx * 64 + ct * 16 + l15)) * 512 + wv * 128) +
                  (unsigned long long)lk * 16;

    const int r = tid >> 2;
    const int uu0 = (tid & 3) * 4;

    for (int t = 0; t < Tt; ++t) {
      // throttle: keep at most NSLOT-2 steps ahead of consumer c
      if (tid == 0 && t >= NSLOT - 2) {
        int gd = 0;
        while (pollSys(&consumed[c * 16]) < (unsigned)(t - (NSLOT - 2)) && ++gd < GUARD)
          __builtin_amdgcn_s_sleep(4);
      }
      __syncthreads();  // X1

      unsigned long long xaddr[4];
#pragma unroll
      for (int mt = 0; mt < 4; ++mt)
        xaddr[mt] = (unsigned long long)(x + ((size_t)(mt * 16 + l15) * Tt + t) * Dd +
                                         half * 512 + wv * 128) +
                    (unsigned long long)lk * 32;
#pragma unroll
      for (int mt = 0; mt < 4; ++mt)
#pragma unroll
        for (int ct = 0; ct < 4; ++ct) acc[mt][ct] = (f32x4){0.f, 0.f, 0.f, 0.f};

      ISSUE_X(s0, 0); ISSUE_X(s1, 1);
      WAITV(12); CONSUME(s0); ISSUE_X(s0, 2);
      WAITV(12); CONSUME(s1); ISSUE_X(s1, 3);
      WAITV(12); CONSUME(s0);
      WAITV(0);  CONSUME(s1);

#pragma unroll
      for (int mt = 0; mt < 4; ++mt)
#pragma unroll
        for (int ct = 0; ct < 4; ++ct)
#pragma unroll
          for (int q = 0; q < 4; ++q)
            ZPART(wv, mt * 16 + lk * 4 + q, ct * 16 + l15) = acc[mt][ct][q];
      __syncthreads();  // X2

      {
        unsigned long long pa = (unsigned long long)(
            xzring + ((size_t)(t & (NSLOT - 1)) * 128 + idx) * 8192 + (size_t)r * 128 + uu0);
#pragma unroll
        for (int g = 0; g < 4; ++g) {
          const int cc = g * 16 + uu0;
          f32x4 s = *reinterpret_cast<const f32x4*>(&ZPART(0, r, cc));
#pragma unroll
          for (int w = 1; w < 4; ++w) {
            f32x4 v = *reinterpret_cast<const f32x4*>(&ZPART(w, r, cc));
            s[0] += v[0]; s[1] += v[1]; s[2] += v[2]; s[3] += v[3];
          }
          STORE16_WT(pa, g * 64, s);
        }
      }
      __syncthreads();  // X3: drains partial stores

      if (tid == 0) storeSys(&xzflag[idx * 16], (unsigned)(t + 1));
    }
  }
}

// ---- launch ----------------------------------------------------------------

extern "C" void kernel_launch(void* const* d_in, const int* in_sizes, int n_in,
                              void* d_out, int out_size, void* d_ws, size_t ws_size,
                              hipStream_t stream) {
  const float* x = (const float*)d_in[0];
  const float* h0 = (const float*)d_in[1];
  const float* c0 = (const float*)d_in[2];
  const float* Wx = (const float*)d_in[3];
  const float* Wh = (const float*)d_in[4];
  const float* bias = (const float*)d_in[5];
  float* out = (float*)d_out;

  char* ws = (char*)d_ws;
  size_t off = 0;
  __hip_bfloat16* pWh = (__hip_bfloat16*)(ws + off); off += (size_t)4 * Uu * Uu * 2;          // 8.4 MB
  __hip_bfloat16* pWx = (__hip_bfloat16*)(ws + off); off += (size_t)4 * Uu * Dd * 2;          // 8.4 MB
  float* xzring = (float*)(ws + off);                off += (size_t)NSLOT * 128 * 8192 * 4;   // 33.5 MB
  unsigned* flagmat = (unsigned*)(ws + off);         off += (size_t)NHW * NHW * 4;            // 16 KB
  unsigned* xzflag = (unsigned*)(ws + off);          off += (size_t)NXW * 64;                 // 8 KB
  unsigned* consumed = (unsigned*)(ws + off);        off += (size_t)NHW * 64;                 // 4 KB

  hipFuncSetAttribute((const void*)lstm_persist,
                      hipFuncAttributeMaxDynamicSharedMemorySize, DYN_LDS);

  pack_wh<<<dim3(4 * Uu / 32, Uu / 32), dim3(32, 8), 0, stream>>>(Wh, pWh);
  pack_wx<<<dim3(4 * Uu / 32, Dd / 32), dim3(32, 8), 0, stream>>>(Wx, pWx);
  hipMemsetAsync(flagmat, 0, (size_t)NHW * NHW * 4 + NXW * 64 + NHW * 64, stream);

  lstm_persist<<<NWG, 256, DYN_LDS, stream>>>(x, pWh, pWx, bias, h0, c0, out,
                                              xzring, flagmat, xzflag, consumed);
}